// Round 10
// baseline (11385.061 us; speedup 1.0000x reference)
//
#include <hip/hip_runtime.h>
#include <math.h>

typedef unsigned int u32;

// ---- output element offsets (d_out is FLOAT32, 101760 elements) ----
#define OUT_ZS    0        // z_smooth [3][127][10]
#define OUT_PS    3810     // P_smooth [3][127][100]
#define OUT_AALL  41910    // a_all    [3][128][5]
#define OUT_A     43830    // A        [128][3][100]
#define OUT_C     82230    // C        [128][3][50]
#define OUT_LASTZ 101430   // last_z   [3][10]
#define OUT_LASTP 101460   // last_P   [3][100]

__device__ __forceinline__ float sigm(float x){ return 1.f/(1.f+expf(-x)); }
__device__ __forceinline__ float safed(float d){
    return (fabsf(d) < 1e-30f) ? ((d < 0.f) ? -1e-30f : 1e-30f) : d;
}

// ---- static device workspace ----
__device__ float r10_c1[25165824];   // [384][32][32][64] NHWC
__device__ float r10_c2[12582912];   // [384][16][16][128]
__device__ float r10_c3[12582912];   // [384][8][8][512]
__device__ float r10_hs[49152];      // [128][3][128]
__device__ float r10_zhat[3840];     // [128][3][10]
__device__ float r10_phat[38400];    // [128][3][100] (clamped)
__device__ float r10_pz[3840];
__device__ float r10_pp[38400];
__device__ float r10_aall[1920];     // [3][128][5]
__device__ float r10_A[38400];       // [128][3][100]
__device__ float r10_C[19200];       // [128][3][50]
__device__ float r10_G[38400];       // [128][3][100]  A^T @ inv(phat)

// ============================ naive conv (k=4, s=2, pad 1) ============================
__global__ __launch_bounds__(256) void convg_r10(const float* __restrict__ in,
        const float* __restrict__ w, const float* __restrict__ bias, float* __restrict__ out,
        int F, int IH, int IW, int IC, int OC)
{
    int OH = IH >> 1, OW = IW >> 1;
    int total = F * OH * OW * OC;
    int idx = blockIdx.x * 256 + threadIdx.x;
    if (idx >= total) return;
    int oc = idx % OC; int r = idx / OC;
    int x = r % OW; r /= OW;
    int y = r % OH; r /= OH;
    int f = r;
    float s = bias[oc];
    for (int ky = 0; ky < 4; ky++) {
        int iy = 2*y - 1 + ky;
        if (iy < 0 || iy >= IH) continue;
        for (int kx = 0; kx < 4; kx++) {
            int ix = 2*x - 1 + kx;
            if (ix < 0 || ix >= IW) continue;
            const float* ip = in + ((f*IH + iy)*(long)IW + ix) * IC;
            const float* wp = w + ((ky*4 + kx)*IC) * OC + oc;
            for (int ic = 0; ic < IC; ic++) s += ip[ic] * wp[ic*OC];
        }
    }
    out[idx] = fmaxf(s, 0.f);
}

// ============================ dense -> a_all (cols 0..4 of wd) ============================
__global__ __launch_bounds__(256) void dense_r10(const float* __restrict__ wd,
        const float* __restrict__ bd, float* __restrict__ dout)
{
    const int f = blockIdx.x, tid = threadIdx.x;
    float p0=0,p1=0,p2=0,p3=0,p4=0;
    const float* x = r10_c3 + f*32768;
    for (int j = tid; j < 32768; j += 256) {
        float v = x[j];
        const float* wp = wd + j*20;
        p0 += v*wp[0]; p1 += v*wp[1]; p2 += v*wp[2]; p3 += v*wp[3]; p4 += v*wp[4];
    }
    __shared__ float red[5][256];
    red[0][tid]=p0; red[1][tid]=p1; red[2][tid]=p2; red[3][tid]=p3; red[4][tid]=p4;
    __syncthreads();
    for (int st = 128; st > 0; st >>= 1) {
        if (tid < st) {
            #pragma unroll
            for (int d = 0; d < 5; d++) red[d][tid] += red[d][tid+st];
        }
        __syncthreads();
    }
    if (tid < 5) {
        float v = red[tid][0] + bd[tid];
        r10_aall[f*5 + tid] = v;
        dout[OUT_AALL + f*5 + tid] = v;
    }
}

// ============================ LSTM ============================
__global__ __launch_bounds__(128) void lstm_r10(const float* __restrict__ lk,
        const float* __restrict__ lrk, const float* __restrict__ lb)
{
    const int b = blockIdx.x, c = threadIdx.x;
    __shared__ float h[128];
    __shared__ float a[5];
    h[c] = 0.f;
    float cs = 0.f;
    __syncthreads();
    for (int t = 0; t < 128; t++) {
        if (c < 5) a[c] = (t == 0) ? 0.f : r10_aall[(b*128 + (t-1))*5 + c];
        __syncthreads();
        float g[4];
        #pragma unroll
        for (int q = 0; q < 4; q++) {
            int col = q*128 + c;
            float s = lb[col];
            for (int d = 0; d < 5; d++)   s += a[d] * lk[d*512 + col];
            for (int j = 0; j < 128; j++) s += h[j] * lrk[j*512 + col];
            g[q] = s;
        }
        __syncthreads();
        float gi = g[0], gf = g[1], gg = g[2], go = g[3];
        cs = sigm(gf)*cs + sigm(gi)*tanhf(gg);
        float hn = sigm(go)*tanhf(cs);
        h[c] = hn;
        r10_hs[(t*3 + b)*128 + c] = hn;
        __syncthreads();
    }
}

// ============================ abc -> A, C ============================
__global__ __launch_bounds__(192) void abc_r10(const float* __restrict__ wabc,
        const float* __restrict__ babc, float* __restrict__ dout)
{
    const int tb = blockIdx.x, c = threadIdx.x;
    __shared__ float h_lds[128];
    if (c < 128) h_lds[c] = r10_hs[tb*128 + c];
    __syncthreads();
    if (c < 150) {
        float s = babc[c];
        for (int j = 0; j < 128; j++) s += h_lds[j]*wabc[j*150 + c];
        if (c < 100) { r10_A[tb*100 + c] = s; dout[OUT_A + tb*100 + c] = s; }
        else         { r10_C[tb*50 + (c-100)] = s; dout[OUT_C + tb*50 + (c-100)] = s; }
    }
}

// ============================ Kalman filter ============================
__global__ __launch_bounds__(128) void kf_r10(float* __restrict__ dout)
{
    const int b = blockIdx.x, tid = threadIdx.x;
    const int i10 = tid/10, j10 = tid%10;
    __shared__ float A[100], C[50], z[10], P[100], zh[10], AP[100], Ph[100],
                     resid[5], CPm[50], Sa[5][11], PCt[50], K[50], pzv[10], Pn[100], av[5];
    if (tid < 100) P[tid] = (i10==j10) ? 1.f : 0.f;
    if (tid < 10) z[tid] = 0.f;
    for (int t = 0; t < 128; t++) {
        __syncthreads();
        if (tid < 100) A[tid] = r10_A[(t*3+b)*100 + tid];
        if (tid < 50)  C[tid] = r10_C[(t*3+b)*50 + tid];
        if (tid < 5)   av[tid] = r10_aall[(b*128+t)*5 + tid];
        __syncthreads();
        if (tid < 10) { float s=0.f; for (int k=0;k<10;k++) s += A[tid*10+k]*z[k]; zh[tid]=s; }
        if (tid < 100){ float s=0.f; for (int k=0;k<10;k++) s += A[i10*10+k]*P[k*10+j10]; AP[tid]=s; }
        __syncthreads();
        if (tid < 100){ float s=(i10==j10)?0.08f:0.f; for (int k=0;k<10;k++) s += AP[i10*10+k]*A[j10*10+k]; Ph[tid]=s; }
        __syncthreads();
        if (tid < 5)  { float s=av[tid]; for (int k=0;k<10;k++) s -= C[tid*10+k]*zh[k]; resid[tid]=s; }
        if (tid < 50) { int i=tid/10, j=tid%10; float s=0.f; for (int k=0;k<10;k++) s += C[i*10+k]*Ph[k*10+j]; CPm[tid]=s; }
        __syncthreads();
        if (tid < 25) { int i=tid/5, j=tid%5; float s=(i==j)?0.03f:0.f; for (int k=0;k<10;k++) s += CPm[i*10+k]*C[j*10+k]; Sa[i][j]=s; }
        if (tid >= 32 && tid < 57) { int q=tid-32, i=q/5, j=q%5; Sa[i][5+j] = (i==j)?1.f:0.f; }
        if (tid >= 64 && tid < 114){ int q=tid-64, i=q/5, j=q%5; float s=0.f; for (int k=0;k<10;k++) s += Ph[i*10+k]*C[j*10+k]; PCt[q]=s; }
        __syncthreads();
        for (int k = 0; k < 5; k++) {
            const int r = tid/10, cc = tid%10;
            float pinv = 1.f/safed(Sa[k][k]);
            float myf = 0.f, rowv = 0.f;
            if (tid < 50) { myf = Sa[r][k]; rowv = Sa[k][cc]; }
            __syncthreads();
            if (tid < 50) {
                if (r == k) Sa[k][cc] = rowv * pinv;
                else        Sa[r][cc] -= myf * pinv * rowv;
            }
            __syncthreads();
        }
        if (tid < 50) { int i=tid/5, j=tid%5; float s=0.f; for (int k=0;k<5;k++) s += PCt[i*5+k]*Sa[k][5+j]; K[tid]=s; }
        __syncthreads();
        if (tid < 10) { float s=zh[tid]; for (int k=0;k<5;k++) s += K[tid*5+k]*resid[k]; pzv[tid]=s; }
        if (tid < 100){ float s=0.f; for (int k=0;k<5;k++) s += K[i10*5+k]*C[k*10+j10]; AP[tid]=s; }  // AP := K@C
        __syncthreads();
        if (tid < 100){ float s=Ph[tid]; for (int k=0;k<10;k++) s -= AP[i10*10+k]*Ph[k*10+j10]; Pn[tid]=s; }
        __syncthreads();
        if (tid < 10) { r10_zhat[(t*3+b)*10+tid]=zh[tid]; r10_pz[(t*3+b)*10+tid]=pzv[tid]; z[tid]=pzv[tid]; }
        if (tid < 100){
            float phc = fmaxf(Ph[tid], (i10==j10)?1e-4f:0.f);   // elementwise max with 1e-4*I
            r10_phat[(t*3+b)*100+tid]=phc;
            r10_pp[(t*3+b)*100+tid]=Pn[tid];
            P[tid]=Pn[tid];
        }
    }
    __syncthreads();
    if (tid < 10)  dout[OUT_LASTZ + b*10 + tid]  = z[tid];
    if (tid < 100) dout[OUT_LASTP + b*100 + tid] = P[tid];
}

// ============================ G = A^T @ inv(Phat_clamped) ============================
__global__ __launch_bounds__(256) void ginv_r10()
{
    const int idx = blockIdx.x;
    const int tt = idx/3 + 1, b = idx%3;   // tt in 1..127
    const int tid = threadIdx.x;
    __shared__ float M[10][21];
    __shared__ float A[100];
    __shared__ int piv;
    if (tid < 100) {
        int i = tid/10, j = tid%10;
        M[i][j] = r10_phat[(tt*3+b)*100 + tid];
        M[i][10+j] = (i==j) ? 1.f : 0.f;
        A[tid] = r10_A[(tt*3+b)*100 + tid];
    }
    __syncthreads();
    const int r = tid/20, cc = tid%20;
    for (int k = 0; k < 10; k++) {
        if (tid == 0) {
            int p = k; float best = fabsf(M[k][k]);
            for (int rr = k+1; rr < 10; rr++) {
                float v = fabsf(M[rr][k]);
                if (v > best) { best = v; p = rr; }
            }
            piv = p;
        }
        __syncthreads();
        if (piv != k && tid < 20) {
            float a = M[k][tid], bb = M[piv][tid];
            M[k][tid] = bb; M[piv][tid] = a;
        }
        __syncthreads();
        float pinv = 1.f/safed(M[k][k]);
        float myf = 0.f, rowv = 0.f;
        if (tid < 200) { myf = M[r][k]; rowv = M[k][cc]; }
        __syncthreads();
        if (tid < 200) {
            if (r == k) M[k][cc] = rowv*pinv;
            else        M[r][cc] -= myf*pinv*rowv;
        }
        __syncthreads();
    }
    if (tid < 100) {
        int i = tid/10, j = tid%10;
        float s = 0.f;
        #pragma unroll
        for (int k = 0; k < 10; k++) s += A[k*10+i]*M[k][10+j];
        r10_G[(tt*3+b)*100 + tid] = s;
    }
}

// ============================ RTS smoother ============================
__global__ __launch_bounds__(128) void rts_r10(float* __restrict__ dout)
{
    const int b = blockIdx.x, tid = threadIdx.x;
    const int i10 = tid/10, j10 = tid%10;
    __shared__ float zc[10], Pc[100], D[100], Gt[100], pPm[100], ph[100],
                     zh[10], pzv[10], dz[10], T1[100], zn[10], Pnn[100];
    if (tid < 10)  zc[tid] = r10_pz[(127*3+b)*10 + tid];
    if (tid < 100) Pc[tid] = r10_pp[(127*3+b)*100 + tid];
    for (int t = 126; t >= 0; t--) {
        __syncthreads();
        if (tid < 100) {
            Gt[tid]  = r10_G[((t+1)*3+b)*100 + tid];
            pPm[tid] = r10_pp[(t*3+b)*100 + tid];
            ph[tid]  = r10_phat[((t+1)*3+b)*100 + tid];
        }
        if (tid < 10) {
            zh[tid]  = r10_zhat[((t+1)*3+b)*10 + tid];
            pzv[tid] = r10_pz[(t*3+b)*10 + tid];
        }
        __syncthreads();
        if (tid < 100){ float s=0.f; for (int k=0;k<10;k++) s += pPm[i10*10+k]*Gt[k*10+j10]; D[tid]=s; }
        if (tid < 10) dz[tid] = zc[tid] - zh[tid];
        __syncthreads();
        if (tid < 10) { float s=pzv[tid]; for (int k=0;k<10;k++) s += D[tid*10+k]*dz[k]; zn[tid]=s; }
        if (tid < 100){ float s=0.f; for (int k=0;k<10;k++) s += D[i10*10+k]*(Pc[k*10+j10]-ph[k*10+j10]); T1[tid]=s; }
        __syncthreads();
        if (tid < 100){ float s=pPm[tid]; for (int k=0;k<10;k++) s += T1[i10*10+k]*D[j10*10+k]; Pnn[tid]=s; }
        __syncthreads();
        if (tid < 10) { dout[OUT_ZS + (b*127+t)*10 + tid] = zn[tid]; zc[tid]=zn[tid]; }
        if (tid < 100){ dout[OUT_PS + (b*127+t)*100 + tid] = Pnn[tid]; Pc[tid]=Pnn[tid]; }
    }
}

// ============================ launch ============================
extern "C" void kernel_launch(void* const* d_in, const int* in_sizes, int n_in,
                              void* d_out, int out_size, void* d_ws, size_t ws_size,
                              hipStream_t stream)
{
    (void)in_sizes; (void)n_in; (void)out_size; (void)d_ws; (void)ws_size;
    const float* images = (const float*)d_in[0];
    const float* w1   = (const float*)d_in[1];
    const float* b1   = (const float*)d_in[2];
    const float* w2   = (const float*)d_in[3];
    const float* b2   = (const float*)d_in[4];
    const float* w3   = (const float*)d_in[5];
    const float* b3   = (const float*)d_in[6];
    const float* wd   = (const float*)d_in[7];
    const float* bd   = (const float*)d_in[8];
    const float* lk   = (const float*)d_in[9];
    const float* lrk  = (const float*)d_in[10];
    const float* lb   = (const float*)d_in[11];
    const float* wabc = (const float*)d_in[12];
    const float* babc = (const float*)d_in[13];
    float* dout = (float*)d_out;   // d_out is FLOAT32 (R10 theory)

    float *c1p, *c2p, *c3p;
    hipGetSymbolAddress((void**)&c1p, HIP_SYMBOL(r10_c1));
    hipGetSymbolAddress((void**)&c2p, HIP_SYMBOL(r10_c2));
    hipGetSymbolAddress((void**)&c3p, HIP_SYMBOL(r10_c3));

    convg_r10<<<dim3(98304), dim3(256), 0, stream>>>(images, w1, b1, c1p, 384, 64, 64, 1, 64);
    convg_r10<<<dim3(49152), dim3(256), 0, stream>>>(c1p, w2, b2, c2p, 384, 32, 32, 64, 128);
    convg_r10<<<dim3(49152), dim3(256), 0, stream>>>(c2p, w3, b3, c3p, 384, 16, 16, 128, 512);
    dense_r10<<<dim3(384), dim3(256), 0, stream>>>(wd, bd, dout);
    lstm_r10<<<dim3(3), dim3(128), 0, stream>>>(lk, lrk, lb);
    abc_r10<<<dim3(384), dim3(192), 0, stream>>>(wabc, babc, dout);
    kf_r10<<<dim3(3), dim3(128), 0, stream>>>(dout);
    ginv_r10<<<dim3(381), dim3(256), 0, stream>>>();
    rts_r10<<<dim3(3), dim3(128), 0, stream>>>(dout);
}

// Round 11
// 3770.245 us; speedup vs baseline: 3.0197x; 3.0197x over previous
//
#include <hip/hip_runtime.h>
#include <math.h>

typedef unsigned int u32;

// ---- output element offsets (d_out is FLOAT32, 101760 elements) ----
#define OUT_ZS    0        // z_smooth [3][127][10]
#define OUT_PS    3810     // P_smooth [3][127][100]
#define OUT_AALL  41910    // a_all    [3][128][5]
#define OUT_A     43830    // A        [128][3][100]
#define OUT_C     82230    // C        [128][3][50]
#define OUT_LASTZ 101430   // last_z   [3][10]
#define OUT_LASTP 101460   // last_P   [3][100]

__device__ __forceinline__ float sigm(float x){ return 1.f/(1.f+expf(-x)); }
__device__ __forceinline__ float safed(float d){
    return (fabsf(d) < 1e-30f) ? ((d < 0.f) ? -1e-30f : 1e-30f) : d;
}

// ---- static device workspace ----
__device__ float r11_c1[25165824];   // conv1 out, planar [f*8+og][1024 pix][8ch]
__device__ float r11_c2[12582912];   // [384][256][128] NHWC
__device__ float r11_c3[12582912];   // [384][64][512] NHWC
__device__ float r11_hs[49152];      // [128][3][128]
__device__ float r11_zhat[3840];     // [128][3][10]
__device__ float r11_phat[38400];    // [128][3][100] (clamped)
__device__ float r11_pz[3840];
__device__ float r11_pp[38400];
__device__ float r11_aall[1920];     // [3][128][5]
__device__ float r11_A[38400];       // [128][3][100]
__device__ float r11_C[19200];       // [128][3][50]
__device__ float r11_G[38400];       // [128][3][100]  A^T @ inv(phat)

// ============================ conv1 (tiled) ============================
// in: images fp32 [f][64][64]; w1 [16][64]; out: fp32 planar [f][g<8][32*32][8]
__global__ __launch_bounds__(256) void conv1_r11(const float* __restrict__ img,
        const float* __restrict__ w1, const float* __restrict__ b1, float* __restrict__ out)
{
    __shared__ float in_lds[66*66];
    const int f = blockIdx.x, tid = threadIdx.x;
    const int og = tid >> 5, sg = tid & 31;

    for (int i = tid; i < 66*66; i += 256) in_lds[i] = 0.f;
    __syncthreads();
    const float4* src = (const float4*)(img + f*4096);
    for (int i = tid; i < 1024; i += 256) {
        int r = i >> 4, c0 = (i & 15) * 4;
        float4 v = src[i];
        float* dst = &in_lds[(r+1)*66 + c0 + 1];
        dst[0]=v.x; dst[1]=v.y; dst[2]=v.z; dst[3]=v.w;
    }
    float wr[16][8];
    #pragma unroll
    for (int k = 0; k < 16; k++) {
        float4 a = *(const float4*)&w1[k*64 + og*8];
        float4 b = *(const float4*)&w1[k*64 + og*8 + 4];
        wr[k][0]=a.x; wr[k][1]=a.y; wr[k][2]=a.z; wr[k][3]=a.w;
        wr[k][4]=b.x; wr[k][5]=b.y; wr[k][6]=b.z; wr[k][7]=b.w;
    }
    float bias[8];
    #pragma unroll
    for (int j = 0; j < 8; j++) bias[j] = b1[og*8+j];
    __syncthreads();

    float* obase = out + (f*8 + og)*8192;   // group og holds channels og*8..og*8+7
    for (int yy = 0; yy < 32; yy++) {
        float inv[16];
        #pragma unroll
        for (int ky = 0; ky < 4; ky++)
            #pragma unroll
            for (int kx = 0; kx < 4; kx++)
                inv[ky*4+kx] = in_lds[(2*yy+ky)*66 + 2*sg+kx];
        float acc[8];
        #pragma unroll
        for (int j = 0; j < 8; j++) acc[j] = bias[j];
        #pragma unroll
        for (int k = 0; k < 16; k++)
            #pragma unroll
            for (int j = 0; j < 8; j++) acc[j] += inv[k]*wr[k][j];
        #pragma unroll
        for (int j = 0; j < 8; j++) acc[j] = fmaxf(acc[j], 0.f);
        float* op = obase + (yy*32+sg)*8;
        *(float4*)(op)   = make_float4(acc[0],acc[1],acc[2],acc[3]);
        *(float4*)(op+4) = make_float4(acc[4],acc[5],acc[6],acc[7]);
    }
}

// ============================ conv2 (tiled) ============================
// in: conv1out planar [f][8][1024][8]; w2 [16][64][128]; out: [f][256][128] NHWC
__global__ __launch_bounds__(256) void conv2_r11(const float* __restrict__ c1,
        const float* __restrict__ w2, const float* __restrict__ b2, float* __restrict__ outp)
{
    __shared__ float in_lds[34*34*8];   // 36,992 B
    const int f = blockIdx.x, ocg = blockIdx.y, tid = threadIdx.x;
    const int sg = tid & 31, og = tid >> 5;
    const int oc0 = ocg*64 + og*8;

    float acc[8][8];
    #pragma unroll
    for (int s = 0; s < 8; s++)
        #pragma unroll
        for (int j = 0; j < 8; j++) acc[s][j] = b2[oc0+j];

    for (int i = tid; i < 34*34*8; i += 256) in_lds[i] = 0.f;
    __syncthreads();

    for (int icg = 0; icg < 8; icg++) {
        const float4* gsrc = (const float4*)(c1 + (f*8 + icg)*8192);
        for (int i = tid; i < 2048; i += 256) {
            int y = i >> 6, r = i & 63;            // row = 32 pix * 8 ch = 64 float4
            ((float4*)&in_lds[((y+1)*34 + 1)*8])[r] = gsrc[i];
        }
        __syncthreads();
        for (int kk = 0; kk < 16; kk++) {
            const int ky = kk >> 2, kx = kk & 3;
            float wr[8][8];
            #pragma unroll
            for (int i2 = 0; i2 < 8; i2++) {
                const float* wp = w2 + (kk*64 + icg*8 + i2)*128 + oc0;
                float4 a = *(const float4*)wp;
                float4 b = *(const float4*)(wp+4);
                wr[i2][0]=a.x; wr[i2][1]=a.y; wr[i2][2]=a.z; wr[i2][3]=a.w;
                wr[i2][4]=b.x; wr[i2][5]=b.y; wr[i2][6]=b.z; wr[i2][7]=b.w;
            }
            #pragma unroll
            for (int s = 0; s < 8; s++) {
                const int id = s*32 + sg, y = id >> 4, x = id & 15;
                const float* ip = &in_lds[((2*y+ky)*34 + (2*x+kx))*8];
                float4 pa = *(const float4*)ip;
                float4 pb = *(const float4*)(ip+4);
                #pragma unroll
                for (int j = 0; j < 8; j++)
                    acc[s][j] += pa.x*wr[0][j] + pa.y*wr[1][j] + pa.z*wr[2][j] + pa.w*wr[3][j]
                               + pb.x*wr[4][j] + pb.y*wr[5][j] + pb.z*wr[6][j] + pb.w*wr[7][j];
            }
        }
        __syncthreads();
    }
    float* ob = outp + f*32768 + oc0;
    #pragma unroll
    for (int s = 0; s < 8; s++) {
        const int id = s*32 + sg, y = id >> 4, x = id & 15;
        float* op = ob + (y*16+x)*128;
        *(float4*)(op)   = make_float4(fmaxf(acc[s][0],0.f), fmaxf(acc[s][1],0.f),
                                       fmaxf(acc[s][2],0.f), fmaxf(acc[s][3],0.f));
        *(float4*)(op+4) = make_float4(fmaxf(acc[s][4],0.f), fmaxf(acc[s][5],0.f),
                                       fmaxf(acc[s][6],0.f), fmaxf(acc[s][7],0.f));
    }
}

// ============================ conv3 (tiled) ============================
// in: conv2out [f][256][128] NHWC; w3 [16][128][512]; out: [f][64][512] NHWC
__global__ __launch_bounds__(256) void conv3_r11(const float* __restrict__ c2,
        const float* __restrict__ w3, const float* __restrict__ b3, float* __restrict__ outp)
{
    __shared__ float in_lds[18*18*32];   // 41,472 B
    const int f = blockIdx.x, ocg = blockIdx.y, tid = threadIdx.x;
    const int sg = tid & 7, og = tid >> 3;
    const int oc0 = ocg*256 + og*8;

    float acc[8][8];
    #pragma unroll
    for (int s = 0; s < 8; s++)
        #pragma unroll
        for (int j = 0; j < 8; j++) acc[s][j] = b3[oc0+j];

    for (int i = tid; i < 18*18*32; i += 256) in_lds[i] = 0.f;
    __syncthreads();

    for (int ich = 0; ich < 4; ich++) {   // 4 groups of 32 input channels
        for (int i = tid; i < 2048; i += 256) {
            int pix = i >> 3, q = i & 7;           // 8 float4 per pixel (32 ch)
            int y = pix >> 4, x = pix & 15;
            ((float4*)&in_lds[((y+1)*18 + (x+1))*32])[q] =
                ((const float4*)(c2 + f*32768 + pix*128 + ich*32))[q];
        }
        __syncthreads();
        for (int kk = 0; kk < 16; kk++) {
            const int ky = kk >> 2, kx = kk & 3;
            for (int icb = 0; icb < 4; icb++) {    // 4 sub-groups of 8 ch
                float wr[8][8];
                #pragma unroll
                for (int i2 = 0; i2 < 8; i2++) {
                    const float* wp = w3 + (kk*128 + ich*32 + icb*8 + i2)*512 + oc0;
                    float4 a = *(const float4*)wp;
                    float4 b = *(const float4*)(wp+4);
                    wr[i2][0]=a.x; wr[i2][1]=a.y; wr[i2][2]=a.z; wr[i2][3]=a.w;
                    wr[i2][4]=b.x; wr[i2][5]=b.y; wr[i2][6]=b.z; wr[i2][7]=b.w;
                }
                #pragma unroll
                for (int s = 0; s < 8; s++) {
                    const float* ip = &in_lds[((2*s+ky)*18 + (2*sg+kx))*32 + icb*8];
                    float4 pa = *(const float4*)ip;
                    float4 pb = *(const float4*)(ip+4);
                    #pragma unroll
                    for (int j = 0; j < 8; j++)
                        acc[s][j] += pa.x*wr[0][j] + pa.y*wr[1][j] + pa.z*wr[2][j] + pa.w*wr[3][j]
                                   + pb.x*wr[4][j] + pb.y*wr[5][j] + pb.z*wr[6][j] + pb.w*wr[7][j];
                }
            }
        }
        __syncthreads();
    }
    float* ob = outp + f*32768 + oc0;
    #pragma unroll
    for (int s = 0; s < 8; s++) {
        float* op = ob + (s*8+sg)*512;
        *(float4*)(op)   = make_float4(fmaxf(acc[s][0],0.f), fmaxf(acc[s][1],0.f),
                                       fmaxf(acc[s][2],0.f), fmaxf(acc[s][3],0.f));
        *(float4*)(op+4) = make_float4(fmaxf(acc[s][4],0.f), fmaxf(acc[s][5],0.f),
                                       fmaxf(acc[s][6],0.f), fmaxf(acc[s][7],0.f));
    }
}

// ============================ dense -> a_all (cols 0..4 of wd) ============================
__global__ __launch_bounds__(256) void dense_r11(const float* __restrict__ wd,
        const float* __restrict__ bd, float* __restrict__ dout)
{
    const int f = blockIdx.x, tid = threadIdx.x;
    float p0=0,p1=0,p2=0,p3=0,p4=0;
    const float* x = r11_c3 + f*32768;
    for (int j = tid; j < 32768; j += 256) {
        float v = x[j];
        const float* wp = wd + j*20;
        p0 += v*wp[0]; p1 += v*wp[1]; p2 += v*wp[2]; p3 += v*wp[3]; p4 += v*wp[4];
    }
    __shared__ float red[5][256];
    red[0][tid]=p0; red[1][tid]=p1; red[2][tid]=p2; red[3][tid]=p3; red[4][tid]=p4;
    __syncthreads();
    for (int st = 128; st > 0; st >>= 1) {
        if (tid < st) {
            #pragma unroll
            for (int d = 0; d < 5; d++) red[d][tid] += red[d][tid+st];
        }
        __syncthreads();
    }
    if (tid < 5) {
        float v = red[tid][0] + bd[tid];
        r11_aall[f*5 + tid] = v;
        dout[OUT_AALL + f*5 + tid] = v;
    }
}

// ============================ LSTM ============================
__global__ __launch_bounds__(128) void lstm_r11(const float* __restrict__ lk,
        const float* __restrict__ lrk, const float* __restrict__ lb)
{
    const int b = blockIdx.x, c = threadIdx.x;
    __shared__ float h[128];
    __shared__ float a[5];
    h[c] = 0.f;
    float cs = 0.f;
    __syncthreads();
    for (int t = 0; t < 128; t++) {
        if (c < 5) a[c] = (t == 0) ? 0.f : r11_aall[(b*128 + (t-1))*5 + c];
        __syncthreads();
        float g[4];
        #pragma unroll
        for (int q = 0; q < 4; q++) {
            int col = q*128 + c;
            float s = lb[col];
            for (int d = 0; d < 5; d++)   s += a[d] * lk[d*512 + col];
            for (int j = 0; j < 128; j++) s += h[j] * lrk[j*512 + col];
            g[q] = s;
        }
        __syncthreads();
        float gi = g[0], gf = g[1], gg = g[2], go = g[3];
        cs = sigm(gf)*cs + sigm(gi)*tanhf(gg);
        float hn = sigm(go)*tanhf(cs);
        h[c] = hn;
        r11_hs[(t*3 + b)*128 + c] = hn;
        __syncthreads();
    }
}

// ============================ abc -> A, C ============================
__global__ __launch_bounds__(192) void abc_r11(const float* __restrict__ wabc,
        const float* __restrict__ babc, float* __restrict__ dout)
{
    const int tb = blockIdx.x, c = threadIdx.x;
    __shared__ float h_lds[128];
    if (c < 128) h_lds[c] = r11_hs[tb*128 + c];
    __syncthreads();
    if (c < 150) {
        float s = babc[c];
        for (int j = 0; j < 128; j++) s += h_lds[j]*wabc[j*150 + c];
        if (c < 100) { r11_A[tb*100 + c] = s; dout[OUT_A + tb*100 + c] = s; }
        else         { r11_C[tb*50 + (c-100)] = s; dout[OUT_C + tb*50 + (c-100)] = s; }
    }
}

// ============================ Kalman filter ============================
__global__ __launch_bounds__(128) void kf_r11(float* __restrict__ dout)
{
    const int b = blockIdx.x, tid = threadIdx.x;
    const int i10 = tid/10, j10 = tid%10;
    __shared__ float A[100], C[50], z[10], P[100], zh[10], AP[100], Ph[100],
                     resid[5], CPm[50], Sa[5][11], PCt[50], K[50], pzv[10], Pn[100], av[5];
    if (tid < 100) P[tid] = (i10==j10) ? 1.f : 0.f;
    if (tid < 10) z[tid] = 0.f;
    for (int t = 0; t < 128; t++) {
        __syncthreads();
        if (tid < 100) A[tid] = r11_A[(t*3+b)*100 + tid];
        if (tid < 50)  C[tid] = r11_C[(t*3+b)*50 + tid];
        if (tid < 5)   av[tid] = r11_aall[(b*128+t)*5 + tid];
        __syncthreads();
        if (tid < 10) { float s=0.f; for (int k=0;k<10;k++) s += A[tid*10+k]*z[k]; zh[tid]=s; }
        if (tid < 100){ float s=0.f; for (int k=0;k<10;k++) s += A[i10*10+k]*P[k*10+j10]; AP[tid]=s; }
        __syncthreads();
        if (tid < 100){ float s=(i10==j10)?0.08f:0.f; for (int k=0;k<10;k++) s += AP[i10*10+k]*A[j10*10+k]; Ph[tid]=s; }
        __syncthreads();
        if (tid < 5)  { float s=av[tid]; for (int k=0;k<10;k++) s -= C[tid*10+k]*zh[k]; resid[tid]=s; }
        if (tid < 50) { int i=tid/10, j=tid%10; float s=0.f; for (int k=0;k<10;k++) s += C[i*10+k]*Ph[k*10+j]; CPm[tid]=s; }
        __syncthreads();
        if (tid < 25) { int i=tid/5, j=tid%5; float s=(i==j)?0.03f:0.f; for (int k=0;k<10;k++) s += CPm[i*10+k]*C[j*10+k]; Sa[i][j]=s; }
        if (tid >= 32 && tid < 57) { int q=tid-32, i=q/5, j=q%5; Sa[i][5+j] = (i==j)?1.f:0.f; }
        if (tid >= 64 && tid < 114){ int q=tid-64, i=q/5, j=q%5; float s=0.f; for (int k=0;k<10;k++) s += Ph[i*10+k]*C[j*10+k]; PCt[q]=s; }
        __syncthreads();
        for (int k = 0; k < 5; k++) {
            const int r = tid/10, cc = tid%10;
            float pinv = 1.f/safed(Sa[k][k]);
            float myf = 0.f, rowv = 0.f;
            if (tid < 50) { myf = Sa[r][k]; rowv = Sa[k][cc]; }
            __syncthreads();
            if (tid < 50) {
                if (r == k) Sa[k][cc] = rowv * pinv;
                else        Sa[r][cc] -= myf * pinv * rowv;
            }
            __syncthreads();
        }
        if (tid < 50) { int i=tid/5, j=tid%5; float s=0.f; for (int k=0;k<5;k++) s += PCt[i*5+k]*Sa[k][5+j]; K[tid]=s; }
        __syncthreads();
        if (tid < 10) { float s=zh[tid]; for (int k=0;k<5;k++) s += K[tid*5+k]*resid[k]; pzv[tid]=s; }
        if (tid < 100){ float s=0.f; for (int k=0;k<5;k++) s += K[i10*5+k]*C[k*10+j10]; AP[tid]=s; }  // AP := K@C
        __syncthreads();
        if (tid < 100){ float s=Ph[tid]; for (int k=0;k<10;k++) s -= AP[i10*10+k]*Ph[k*10+j10]; Pn[tid]=s; }
        __syncthreads();
        if (tid < 10) { r11_zhat[(t*3+b)*10+tid]=zh[tid]; r11_pz[(t*3+b)*10+tid]=pzv[tid]; z[tid]=pzv[tid]; }
        if (tid < 100){
            float phc = fmaxf(Ph[tid], (i10==j10)?1e-4f:0.f);   // elementwise max with 1e-4*I
            r11_phat[(t*3+b)*100+tid]=phc;
            r11_pp[(t*3+b)*100+tid]=Pn[tid];
            P[tid]=Pn[tid];
        }
    }
    __syncthreads();
    if (tid < 10)  dout[OUT_LASTZ + b*10 + tid]  = z[tid];
    if (tid < 100) dout[OUT_LASTP + b*100 + tid] = P[tid];
}

// ============================ G = A^T @ inv(Phat_clamped) ============================
__global__ __launch_bounds__(256) void ginv_r11()
{
    const int idx = blockIdx.x;
    const int tt = idx/3 + 1, b = idx%3;   // tt in 1..127
    const int tid = threadIdx.x;
    __shared__ float M[10][21];
    __shared__ float A[100];
    __shared__ int piv;
    if (tid < 100) {
        int i = tid/10, j = tid%10;
        M[i][j] = r11_phat[(tt*3+b)*100 + tid];
        M[i][10+j] = (i==j) ? 1.f : 0.f;
        A[tid] = r11_A[(tt*3+b)*100 + tid];
    }
    __syncthreads();
    const int r = tid/20, cc = tid%20;
    for (int k = 0; k < 10; k++) {
        if (tid == 0) {
            int p = k; float best = fabsf(M[k][k]);
            for (int rr = k+1; rr < 10; rr++) {
                float v = fabsf(M[rr][k]);
                if (v > best) { best = v; p = rr; }
            }
            piv = p;
        }
        __syncthreads();
        if (piv != k && tid < 20) {
            float a = M[k][tid], bb = M[piv][tid];
            M[k][tid] = bb; M[piv][tid] = a;
        }
        __syncthreads();
        float pinv = 1.f/safed(M[k][k]);
        float myf = 0.f, rowv = 0.f;
        if (tid < 200) { myf = M[r][k]; rowv = M[k][cc]; }
        __syncthreads();
        if (tid < 200) {
            if (r == k) M[k][cc] = rowv*pinv;
            else        M[r][cc] -= myf*pinv*rowv;
        }
        __syncthreads();
    }
    if (tid < 100) {
        int i = tid/10, j = tid%10;
        float s = 0.f;
        #pragma unroll
        for (int k = 0; k < 10; k++) s += A[k*10+i]*M[k][10+j];
        r11_G[(tt*3+b)*100 + tid] = s;
    }
}

// ============================ RTS smoother ============================
__global__ __launch_bounds__(128) void rts_r11(float* __restrict__ dout)
{
    const int b = blockIdx.x, tid = threadIdx.x;
    const int i10 = tid/10, j10 = tid%10;
    __shared__ float zc[10], Pc[100], D[100], Gt[100], pPm[100], ph[100],
                     zh[10], pzv[10], dz[10], T1[100], zn[10], Pnn[100];
    if (tid < 10)  zc[tid] = r11_pz[(127*3+b)*10 + tid];
    if (tid < 100) Pc[tid] = r11_pp[(127*3+b)*100 + tid];
    for (int t = 126; t >= 0; t--) {
        __syncthreads();
        if (tid < 100) {
            Gt[tid]  = r11_G[((t+1)*3+b)*100 + tid];
            pPm[tid] = r11_pp[(t*3+b)*100 + tid];
            ph[tid]  = r11_phat[((t+1)*3+b)*100 + tid];
        }
        if (tid < 10) {
            zh[tid]  = r11_zhat[((t+1)*3+b)*10 + tid];
            pzv[tid] = r11_pz[(t*3+b)*10 + tid];
        }
        __syncthreads();
        if (tid < 100){ float s=0.f; for (int k=0;k<10;k++) s += pPm[i10*10+k]*Gt[k*10+j10]; D[tid]=s; }
        if (tid < 10) dz[tid] = zc[tid] - zh[tid];
        __syncthreads();
        if (tid < 10) { float s=pzv[tid]; for (int k=0;k<10;k++) s += D[tid*10+k]*dz[k]; zn[tid]=s; }
        if (tid < 100){ float s=0.f; for (int k=0;k<10;k++) s += D[i10*10+k]*(Pc[k*10+j10]-ph[k*10+j10]); T1[tid]=s; }
        __syncthreads();
        if (tid < 100){ float s=pPm[tid]; for (int k=0;k<10;k++) s += T1[i10*10+k]*D[j10*10+k]; Pnn[tid]=s; }
        __syncthreads();
        if (tid < 10) { dout[OUT_ZS + (b*127+t)*10 + tid] = zn[tid]; zc[tid]=zn[tid]; }
        if (tid < 100){ dout[OUT_PS + (b*127+t)*100 + tid] = Pnn[tid]; Pc[tid]=Pnn[tid]; }
    }
}

// ============================ launch ============================
extern "C" void kernel_launch(void* const* d_in, const int* in_sizes, int n_in,
                              void* d_out, int out_size, void* d_ws, size_t ws_size,
                              hipStream_t stream)
{
    (void)in_sizes; (void)n_in; (void)out_size; (void)d_ws; (void)ws_size;
    const float* images = (const float*)d_in[0];
    const float* w1   = (const float*)d_in[1];
    const float* b1   = (const float*)d_in[2];
    const float* w2   = (const float*)d_in[3];
    const float* b2   = (const float*)d_in[4];
    const float* w3   = (const float*)d_in[5];
    const float* b3   = (const float*)d_in[6];
    const float* wd   = (const float*)d_in[7];
    const float* bd   = (const float*)d_in[8];
    const float* lk   = (const float*)d_in[9];
    const float* lrk  = (const float*)d_in[10];
    const float* lb   = (const float*)d_in[11];
    const float* wabc = (const float*)d_in[12];
    const float* babc = (const float*)d_in[13];
    float* dout = (float*)d_out;   // d_out is FLOAT32 (verified R10)

    float *c1p, *c2p, *c3p;
    hipGetSymbolAddress((void**)&c1p, HIP_SYMBOL(r11_c1));
    hipGetSymbolAddress((void**)&c2p, HIP_SYMBOL(r11_c2));
    hipGetSymbolAddress((void**)&c3p, HIP_SYMBOL(r11_c3));

    conv1_r11<<<dim3(384), dim3(256), 0, stream>>>(images, w1, b1, c1p);
    conv2_r11<<<dim3(384,2), dim3(256), 0, stream>>>(c1p, w2, b2, c2p);
    conv3_r11<<<dim3(384,2), dim3(256), 0, stream>>>(c2p, w3, b3, c3p);
    dense_r11<<<dim3(384), dim3(256), 0, stream>>>(wd, bd, dout);
    lstm_r11<<<dim3(3), dim3(128), 0, stream>>>(lk, lrk, lb);
    abc_r11<<<dim3(384), dim3(192), 0, stream>>>(wabc, babc, dout);
    kf_r11<<<dim3(3), dim3(128), 0, stream>>>(dout);
    ginv_r11<<<dim3(381), dim3(256), 0, stream>>>();
    rts_r11<<<dim3(3), dim3(128), 0, stream>>>(dout);
}